// Round 9
// baseline (231.407 us; speedup 1.0000x reference)
//
#include <hip/hip_runtime.h>
#include <hip/hip_bf16.h>
#include <cstdint>
#include <cstddef>

typedef __bf16 bf16;
typedef bf16 bf16x4 __attribute__((ext_vector_type(4)));
typedef bf16 bf16x8 __attribute__((ext_vector_type(8)));
typedef float f32x4 __attribute__((ext_vector_type(4)));

#define MFMA_BF16(a,b,c) __builtin_amdgcn_mfma_f32_16x16x32_bf16((a),(b),(c),0,0,0)

typedef __attribute__((address_space(1))) const void gvoid;
typedef __attribute__((address_space(3))) void svoid;
__device__ __forceinline__ void gload16(const bf16* g, bf16* l){
  __builtin_amdgcn_global_load_lds((gvoid*)g, (svoid*)l, 16, 0, 0);
}

// HEAD_COUNTS = [8,6,4,4,6,4] -> boundaries 8,14,18,22,28,32
__device__ __forceinline__ int head_group(int h){
  return (h<8)?0:(h<14)?1:(h<18)?2:(h<22)?3:(h<28)?4:5;
}

// ---------------- fused f32 -> bf16 convert: 6 tensors in one launch ----------------
struct CvtArgs { const float* src[6]; bf16* dst[6]; };
__global__ __launch_bounds__(256) void cvt6_kernel(CvtArgs a, int n){
  const int z = blockIdx.y;
  const float* __restrict__ in = a.src[z];
  bf16* __restrict__ out = a.dst[z];
  int i = (blockIdx.x*256 + threadIdx.x)*8;
  if (i >= n) return;
  const float4* p = (const float4*)(in + i);
  float4 va = p[0], vb = p[1];
  bf16x8 o;
  o[0]=(bf16)va.x; o[1]=(bf16)va.y; o[2]=(bf16)va.z; o[3]=(bf16)va.w;
  o[4]=(bf16)vb.x; o[5]=(bf16)vb.y; o[6]=(bf16)vb.z; o[7]=(bf16)vb.w;
  *(bf16x8*)(out+i) = o;
}

// ---------------- RoPE cos/sin tables: [T][32] f32 ----------------
__global__ __launch_bounds__(256) void rope_tab_kernel(float* __restrict__ cosT,
                                                       float* __restrict__ sinT){
  const int t = blockIdx.x*8 + (threadIdx.x>>5);
  const int i = threadIdx.x&31;
  float invf = powf(10000.0f, -((float)i)/32.0f);
  float ang = (float)t * invf;
  cosT[t*32+i] = cosf(ang);
  sinT[t*32+i] = sinf(ang);
}

// ---------------- GEMM core: acc = A[M,K] * B[N,K]^T, 128x128 tile ----------------
// m97 structure: BK=32, linear LDS, global_load_lds width=16, 2 barriers/K-step.
__device__ __forceinline__ void gemm_core(const bf16* __restrict__ A,
                                          const bf16* __restrict__ B,
                                          int row0, int col0,
                                          f32x4 (&acc)[4][4]){
  __shared__ bf16 As[128*32];
  __shared__ bf16 Bs[128*32];
  const int tid  = threadIdx.x;
  const int wave = tid>>6, lane = tid&63;
  const int l16  = lane&15, lg = lane>>4;
  const int wr   = wave>>1, wc = wave&1;

  const bf16* Ag0 = A + (size_t)(row0 + wave*32      + (lane>>2))*2048 + (lane&3)*8;
  const bf16* Ag1 = A + (size_t)(row0 + wave*32 + 16 + (lane>>2))*2048 + (lane&3)*8;
  const bf16* Bg0 = B + (size_t)(col0 + wave*32      + (lane>>2))*2048 + (lane&3)*8;
  const bf16* Bg1 = B + (size_t)(col0 + wave*32 + 16 + (lane>>2))*2048 + (lane&3)*8;
  bf16* AsB0 = As + (wave*32     )*32;
  bf16* AsB1 = As + (wave*32 + 16)*32;
  bf16* BsB0 = Bs + (wave*32     )*32;
  bf16* BsB1 = Bs + (wave*32 + 16)*32;

  #pragma unroll
  for (int m=0;m<4;++m)
    #pragma unroll
    for (int n=0;n<4;++n)
      #pragma unroll
      for (int r=0;r<4;++r) acc[m][n][r] = 0.f;

  for (int kt=0; kt<64; ++kt){
    const int ko = kt*32;
    gload16(Ag0 + ko, AsB0);
    gload16(Ag1 + ko, AsB1);
    gload16(Bg0 + ko, BsB0);
    gload16(Bg1 + ko, BsB1);
    __syncthreads();
    bf16x8 af[4], bfr[4];
    #pragma unroll
    for (int m=0;m<4;++m) af[m]  = *(const bf16x8*)&As[(wr*64+m*16+l16)*32 + lg*8];
    #pragma unroll
    for (int n=0;n<4;++n) bfr[n] = *(const bf16x8*)&Bs[(wc*64+n*16+l16)*32 + lg*8];
    #pragma unroll
    for (int m=0;m<4;++m)
      #pragma unroll
      for (int n=0;n<4;++n)
        acc[m][n] = MFMA_BF16(af[m], bfr[n], acc[m][n]);
    __syncthreads();
  }
}

// ---------------- QKV GEMM with fused RoPE / relayout / V-transpose epilogues ----------------
__global__ __launch_bounds__(256) void gemm_qkv_kernel(
    const bf16* __restrict__ A,
    const bf16* __restrict__ B0, const bf16* __restrict__ B1, const bf16* __restrict__ B2,
    bf16* __restrict__ Qs, bf16* __restrict__ Ks, bf16* __restrict__ Vt,
    const float* __restrict__ cosT, const float* __restrict__ sinT,
    const float* __restrict__ mw, const float* __restrict__ ts){
  const int z = blockIdx.z;
  const bf16* B = (z==0)?B0:((z==1)?B1:B2);
  const int row0 = blockIdx.y*128, col0 = blockIdx.x*128;

  f32x4 acc[4][4];
  gemm_core(A, B, row0, col0, acc);

  const int tid  = threadIdx.x;
  const int wave = tid>>6, lane = tid&63;
  const int l16  = lane&15, lg = lane>>4;
  const int wr   = wave>>1, wc = wave&1;
  const int h    = (col0 + wc*64) >> 6;      // wave's 64-col span = one head

  if (z == 2){
    // V-transpose epilogue: acc[m][n][0..3] = 4 consecutive t -> one 8B store
    #pragma unroll
    for (int n=0;n<4;++n){
      const int d = n*16 + l16;
      #pragma unroll
      for (int m=0;m<4;++m){
        const int t0 = row0 + wr*64 + m*16 + lg*4;
        bf16x4 v;
        #pragma unroll
        for (int r=0;r<4;++r) v[r] = (bf16)acc[m][n][r];
        *(bf16x4*)&Vt[((size_t)h*64 + d)*2048 + t0] = v;
      }
    }
  } else {
    const float sc = (z==0) ? 0.125f*ts[h]*mw[head_group(h)] : 1.0f;
    bf16* Out = (z==0) ? Qs : Ks;
    #pragma unroll
    for (int m=0;m<4;++m){
      #pragma unroll
      for (int r=0;r<4;++r){
        const int t = row0 + wr*64 + m*16 + lg*4 + r;
        const float* ct = cosT + t*32;
        const float* st = sinT + t*32;
        bf16* dst = Out + ((size_t)h*2048 + t)*64;
        #pragma unroll
        for (int n=0;n<2;++n){
          const int i = n*16 + l16;
          const float c = ct[i], s = st[i];
          const float a1 = acc[m][n][r], a2 = acc[m][n+2][r];
          dst[i]    = (bf16)((a1*c - a2*s)*sc);
          dst[i+32] = (bf16)((a2*c + a1*s)*sc);
        }
      }
    }
  }
}

__global__ __launch_bounds__(256) void gemm_out_kernel(
    const bf16* __restrict__ A, const bf16* __restrict__ B, float* __restrict__ C){
  const int row0 = blockIdx.y*128, col0 = blockIdx.x*128;
  f32x4 acc[4][4];
  gemm_core(A, B, row0, col0, acc);
  const int tid  = threadIdx.x;
  const int wave = tid>>6, lane = tid&63;
  const int l16  = lane&15, lg = lane>>4;
  const int wr   = wave>>1, wc = wave&1;
  #pragma unroll
  for (int m=0;m<4;++m)
    #pragma unroll
    for (int n=0;n<4;++n)
      #pragma unroll
      for (int r=0;r<4;++r){
        size_t idx = (size_t)(row0 + wr*64 + m*16 + lg*4 + r)*2048
                   + col0 + wc*64 + n*16 + l16;
        C[idx] = acc[m][n][r];
      }
}

// ---------------- fused causal attention: wave-independent, zero barriers ----------------
// 256 blocks x 8 waves; each wave = one 32-row q-tile of one head, processing its
// causal key range in 64-key tiles. K/V/bias read直接 from L2/L3 into fragments
// (formulas identical to the validated round-1 direct-read kernel). K fragments
// double-buffered (ping-pong, static indexing). LDS = per-wave P scratch only.
// Wave->qtile map jj=8w+s mixes long/short waves per block; heads grouped 4/XCD.
struct AttnCtx {
  const bf16 *Kb, *Vb, *Bb;
  float w_h;
  int l16, lg, qw;
};

__device__ __forceinline__ void attn_tile(
    int kt, int ntiles, const AttnCtx& cx,
    bf16x8 (&kc)[4][2], bf16x8 (&kn)[4][2],
    const bf16x8 (&qf)[2][2],
    f32x4 (&O)[2][4], float (&l)[2][4],
    bf16 (*pl)[72]){
  const int k0 = kt*64;
  // prefetch next K tile fragments (ping-pong)
  if (kt+1 < ntiles){
    #pragma unroll
    for (int c=0;c<4;++c){
      const bf16* p = cx.Kb + (size_t)(k0+64 + c*16 + cx.l16)*64 + cx.lg*8;
      kn[c][0] = *(const bf16x8*)p;
      kn[c][1] = *(const bf16x8*)(p+32);
    }
  }
  // current V tile fragments (consumed after QK+exp, ~300cy of hiding)
  bf16x8 vf[4][2];
  #pragma unroll
  for (int c=0;c<4;++c){
    const bf16* p = cx.Vb + (size_t)(c*16+cx.l16)*2048 + k0 + cx.lg*8;
    vf[c][0] = *(const bf16x8*)p;
    vf[c][1] = *(const bf16x8*)(p+32);
  }
  // current bias (bf16, w_h folded)
  float bv[2][4][4];
  #pragma unroll
  for (int m=0;m<2;++m)
    #pragma unroll
    for (int c=0;c<4;++c)
      #pragma unroll
      for (int r=0;r<4;++r)
        bv[m][c][r] = cx.w_h * (float)cx.Bb[(size_t)(m*16+cx.lg*4+r)*2048 + k0 + c*16 + cx.l16];

  // S = w*bias + Q K^T
  f32x4 S[2][4];
  #pragma unroll
  for (int m=0;m<2;++m)
    #pragma unroll
    for (int c=0;c<4;++c)
      #pragma unroll
      for (int r=0;r<4;++r) S[m][c][r] = bv[m][c][r];
  __builtin_amdgcn_s_setprio(1);
  #pragma unroll
  for (int c=0;c<4;++c)
    #pragma unroll
    for (int m=0;m<2;++m){
      S[m][c] = MFMA_BF16(qf[m][0], kc[c][0], S[m][c]);
      S[m][c] = MFMA_BF16(qf[m][1], kc[c][1], S[m][c]);
    }
  __builtin_amdgcn_s_setprio(0);

  // exp (fixed shift); per-element causal mask only on the final tile
  if (kt == ntiles-1){
    #pragma unroll
    for (int m=0;m<2;++m)
      #pragma unroll
      for (int c=0;c<4;++c){
        const int kg = k0 + c*16 + cx.l16;
        const int qg = cx.qw + m*16 + cx.lg*4;
        #pragma unroll
        for (int r=0;r<4;++r){
          float p = __expf(S[m][c][r] - 4.0f);
          if (kg > qg + r) p = 0.f;
          S[m][c][r] = p; l[m][r] += p;
        }
      }
  } else {
    #pragma unroll
    for (int m=0;m<2;++m)
      #pragma unroll
      for (int c=0;c<4;++c)
        #pragma unroll
        for (int r=0;r<4;++r){
          const float p = __expf(S[m][c][r] - 4.0f);
          S[m][c][r] = p; l[m][r] += p;
        }
  }

  // P (C-layout) -> per-wave LDS scratch -> A-fragments
  #pragma unroll
  for (int m=0;m<2;++m)
    #pragma unroll
    for (int c=0;c<4;++c)
      #pragma unroll
      for (int r=0;r<4;++r)
        pl[m*16+cx.lg*4+r][c*16+cx.l16] = (bf16)S[m][c][r];
  bf16x8 pf[2][2];
  #pragma unroll
  for (int m=0;m<2;++m){
    pf[m][0] = *(const bf16x8*)&pl[m*16+cx.l16][cx.lg*8];
    pf[m][1] = *(const bf16x8*)&pl[m*16+cx.l16][32+cx.lg*8];
  }

  // O += P * V
  __builtin_amdgcn_s_setprio(1);
  #pragma unroll
  for (int c=0;c<4;++c)
    #pragma unroll
    for (int m=0;m<2;++m){
      O[m][c] = MFMA_BF16(pf[m][0], vf[c][0], O[m][c]);
      O[m][c] = MFMA_BF16(pf[m][1], vf[c][1], O[m][c]);
    }
  __builtin_amdgcn_s_setprio(0);
}

__global__ __launch_bounds__(512) void attn_kernel(
    const bf16* __restrict__ Qs, const bf16* __restrict__ Ks,
    const bf16* __restrict__ Vt, const bf16* __restrict__ biasb,
    const float* __restrict__ mw, bf16* __restrict__ attout){
  const int bid = blockIdx.x;                       // 0..255
  const int h   = (bid&7)*4 + ((bid>>3)&3);         // 4 heads per XCD slot
  const int s   = bid>>5;                           // 0..7
  const int tid = threadIdx.x, wid = tid>>6, lane = tid&63;
  const int l16 = lane&15, lg = lane>>4;
  const int jj  = wid*8 + s;                        // wave's 32-row q-tile, 0..63
  const int qw  = jj*32;
  const int ntiles = (jj>>1) + 1;                   // 64-key tiles in causal range

  __shared__ bf16 plds[8][32][72];

  AttnCtx cx;
  cx.Kb = Ks + (size_t)h*2048*64;
  cx.Vb = Vt + (size_t)h*64*2048;
  cx.Bb = biasb + (size_t)qw*2048;
  cx.w_h = mw[head_group(h)];
  cx.l16 = l16; cx.lg = lg; cx.qw = qw;

  // Q fragments (registers, whole kernel)
  bf16x8 qf[2][2];
  #pragma unroll
  for (int m=0;m<2;++m){
    const bf16* Qp = Qs + ((size_t)h*2048 + qw + m*16 + l16)*64 + lg*8;
    qf[m][0] = *(const bf16x8*)Qp;
    qf[m][1] = *(const bf16x8*)(Qp + 32);
  }

  f32x4 O[2][4];
  float l[2][4];
  #pragma unroll
  for (int m=0;m<2;++m)
    #pragma unroll
    for (int c=0;c<4;++c){
      #pragma unroll
      for (int r=0;r<4;++r) O[m][c][r] = 0.f;
      l[m][c] = 0.f;
    }

  // K tile 0 fragments
  bf16x8 ka[4][2], kb2[4][2];
  #pragma unroll
  for (int c=0;c<4;++c){
    const bf16* p = cx.Kb + (size_t)(c*16 + l16)*64 + lg*8;
    ka[c][0] = *(const bf16x8*)p;
    ka[c][1] = *(const bf16x8*)(p+32);
  }

  int kt = 0;
  while (true){
    attn_tile(kt, ntiles, cx, ka, kb2, qf, O, l, plds[wid]);
    if (++kt >= ntiles) break;
    attn_tile(kt, ntiles, cx, kb2, ka, qf, O, l, plds[wid]);
    if (++kt >= ntiles) break;
  }

  // deferred row-sum reduction (across the 16 lanes of each row group)
  #pragma unroll
  for (int m=0;m<2;++m)
    #pragma unroll
    for (int r=0;r<4;++r){
      float v = l[m][r];
      v += __shfl_xor(v,1);
      v += __shfl_xor(v,2);
      v += __shfl_xor(v,4);
      v += __shfl_xor(v,8);
      l[m][r] = 1.0f / v;
    }
  #pragma unroll
  for (int m=0;m<2;++m)
    #pragma unroll
    for (int c=0;c<4;++c)
      #pragma unroll
      for (int r=0;r<4;++r)
        attout[(size_t)(qw + m*16 + lg*4 + r)*2048 + h*64 + c*16 + l16]
          = (bf16)(O[m][c][r]*l[m][r]);
}

// ---------------- launcher ----------------
extern "C" void kernel_launch(void* const* d_in, const int* in_sizes, int n_in,
                              void* d_out, int out_size, void* d_ws, size_t ws_size,
                              hipStream_t stream){
  const float* x    = (const float*)d_in[0];
  const float* bias = (const float*)d_in[2];
  const float* mw   = (const float*)d_in[3];
  const float* Wq   = (const float*)d_in[4];
  const float* Wk   = (const float*)d_in[5];
  const float* Wv   = (const float*)d_in[6];
  const float* Wo   = (const float*)d_in[7];
  const float* ts   = (const float*)d_in[8];
  float* out = (float*)d_out;

  const size_t SZ = (size_t)2048*2048;
  bf16* base = (bf16*)d_ws;
  bf16* xb   = base;
  bf16* Wqb  = base + 1*SZ;
  bf16* Wkb  = base + 2*SZ;
  bf16* Wvb  = base + 3*SZ;
  bf16* Wob  = base + 4*SZ;
  bf16* bb   = base + 5*SZ;
  bf16* Qsb  = base + 6*SZ;
  bf16* Ksb  = base + 7*SZ;
  bf16* Vtb  = base + 8*SZ;
  bf16* att  = base + 9*SZ;
  float* cosT = (float*)(base + 10*SZ);
  float* sinT = cosT + 2048*32;

  CvtArgs ca;
  ca.src[0]=x;  ca.src[1]=Wq;  ca.src[2]=Wk;  ca.src[3]=Wv;  ca.src[4]=Wo;  ca.src[5]=bias;
  ca.dst[0]=xb; ca.dst[1]=Wqb; ca.dst[2]=Wkb; ca.dst[3]=Wvb; ca.dst[4]=Wob; ca.dst[5]=bb;
  const int nb = (int)(SZ/8/256);
  cvt6_kernel<<<dim3(nb,6),256,0,stream>>>(ca, (int)SZ);
  rope_tab_kernel<<<256,256,0,stream>>>(cosT, sinT);
  gemm_qkv_kernel<<<dim3(16,16,3),256,0,stream>>>(xb, Wqb,Wkb,Wvb,
                                                  Qsb,Ksb,Vtb, cosT,sinT, mw,ts);
  attn_kernel<<<256,512,0,stream>>>(Qsb,Ksb,Vtb,bb,mw,att);
  gemm_out_kernel<<<dim3(16,16),256,0,stream>>>(att, Wob, out);
}

// Round 10
// 182.900 us; speedup vs baseline: 1.2652x; 1.2652x over previous
//
#include <hip/hip_runtime.h>
#include <hip/hip_bf16.h>
#include <cstdint>
#include <cstddef>

typedef __bf16 bf16;
typedef bf16 bf16x4 __attribute__((ext_vector_type(4)));
typedef bf16 bf16x8 __attribute__((ext_vector_type(8)));
typedef float f32x4 __attribute__((ext_vector_type(4)));

#define MFMA_BF16(a,b,c) __builtin_amdgcn_mfma_f32_16x16x32_bf16((a),(b),(c),0,0,0)

typedef __attribute__((address_space(1))) const void gvoid;
typedef __attribute__((address_space(3))) void svoid;
__device__ __forceinline__ void gload16(const bf16* g, bf16* l){
  __builtin_amdgcn_global_load_lds((gvoid*)g, (svoid*)l, 16, 0, 0);
}

// HEAD_COUNTS = [8,6,4,4,6,4] -> boundaries 8,14,18,22,28,32
__device__ __forceinline__ int head_group(int h){
  return (h<8)?0:(h<14)?1:(h<18)?2:(h<22)?3:(h<28)?4:5;
}

// ---------------- fused f32 -> bf16 convert: 6 tensors in one launch ----------------
struct CvtArgs { const float* src[6]; bf16* dst[6]; };
__global__ __launch_bounds__(256) void cvt6_kernel(CvtArgs a, int n){
  const int z = blockIdx.y;
  const float* __restrict__ in = a.src[z];
  bf16* __restrict__ out = a.dst[z];
  int i = (blockIdx.x*256 + threadIdx.x)*8;
  if (i >= n) return;
  const float4* p = (const float4*)(in + i);
  float4 va = p[0], vb = p[1];
  bf16x8 o;
  o[0]=(bf16)va.x; o[1]=(bf16)va.y; o[2]=(bf16)va.z; o[3]=(bf16)va.w;
  o[4]=(bf16)vb.x; o[5]=(bf16)vb.y; o[6]=(bf16)vb.z; o[7]=(bf16)vb.w;
  *(bf16x8*)(out+i) = o;
}

// ---------------- RoPE cos/sin tables: [T][32] f32 ----------------
__global__ __launch_bounds__(256) void rope_tab_kernel(float* __restrict__ cosT,
                                                       float* __restrict__ sinT){
  const int t = blockIdx.x*8 + (threadIdx.x>>5);
  const int i = threadIdx.x&31;
  float invf = powf(10000.0f, -((float)i)/32.0f);
  float ang = (float)t * invf;
  cosT[t*32+i] = cosf(ang);
  sinT[t*32+i] = sinf(ang);
}

// ---------------- GEMM core: acc = A[M,K] * B[N,K]^T, 128x128 tile ----------------
// m97 structure: BK=32, linear LDS, global_load_lds width=16, 2 barriers/K-step.
__device__ __forceinline__ void gemm_core(const bf16* __restrict__ A,
                                          const bf16* __restrict__ B,
                                          int row0, int col0,
                                          f32x4 (&acc)[4][4]){
  __shared__ bf16 As[128*32];
  __shared__ bf16 Bs[128*32];
  const int tid  = threadIdx.x;
  const int wave = tid>>6, lane = tid&63;
  const int l16  = lane&15, lg = lane>>4;
  const int wr   = wave>>1, wc = wave&1;

  const bf16* Ag0 = A + (size_t)(row0 + wave*32      + (lane>>2))*2048 + (lane&3)*8;
  const bf16* Ag1 = A + (size_t)(row0 + wave*32 + 16 + (lane>>2))*2048 + (lane&3)*8;
  const bf16* Bg0 = B + (size_t)(col0 + wave*32      + (lane>>2))*2048 + (lane&3)*8;
  const bf16* Bg1 = B + (size_t)(col0 + wave*32 + 16 + (lane>>2))*2048 + (lane&3)*8;
  bf16* AsB0 = As + (wave*32     )*32;
  bf16* AsB1 = As + (wave*32 + 16)*32;
  bf16* BsB0 = Bs + (wave*32     )*32;
  bf16* BsB1 = Bs + (wave*32 + 16)*32;

  #pragma unroll
  for (int m=0;m<4;++m)
    #pragma unroll
    for (int n=0;n<4;++n)
      #pragma unroll
      for (int r=0;r<4;++r) acc[m][n][r] = 0.f;

  for (int kt=0; kt<64; ++kt){
    const int ko = kt*32;
    gload16(Ag0 + ko, AsB0);
    gload16(Ag1 + ko, AsB1);
    gload16(Bg0 + ko, BsB0);
    gload16(Bg1 + ko, BsB1);
    __syncthreads();
    bf16x8 af[4], bfr[4];
    #pragma unroll
    for (int m=0;m<4;++m) af[m]  = *(const bf16x8*)&As[(wr*64+m*16+l16)*32 + lg*8];
    #pragma unroll
    for (int n=0;n<4;++n) bfr[n] = *(const bf16x8*)&Bs[(wc*64+n*16+l16)*32 + lg*8];
    #pragma unroll
    for (int m=0;m<4;++m)
      #pragma unroll
      for (int n=0;n<4;++n)
        acc[m][n] = MFMA_BF16(af[m], bfr[n], acc[m][n]);
    __syncthreads();
  }
}

// ---------------- QKV GEMM with fused RoPE / relayout / V-transpose epilogues ----------------
__global__ __launch_bounds__(256) void gemm_qkv_kernel(
    const bf16* __restrict__ A,
    const bf16* __restrict__ B0, const bf16* __restrict__ B1, const bf16* __restrict__ B2,
    bf16* __restrict__ Qs, bf16* __restrict__ Ks, bf16* __restrict__ Vt,
    const float* __restrict__ cosT, const float* __restrict__ sinT,
    const float* __restrict__ mw, const float* __restrict__ ts){
  const int z = blockIdx.z;
  const bf16* B = (z==0)?B0:((z==1)?B1:B2);
  const int row0 = blockIdx.y*128, col0 = blockIdx.x*128;

  f32x4 acc[4][4];
  gemm_core(A, B, row0, col0, acc);

  const int tid  = threadIdx.x;
  const int wave = tid>>6, lane = tid&63;
  const int l16  = lane&15, lg = lane>>4;
  const int wr   = wave>>1, wc = wave&1;
  const int h    = (col0 + wc*64) >> 6;      // wave's 64-col span = one head

  if (z == 2){
    // V-transpose epilogue: acc[m][n][0..3] = 4 consecutive t -> one 8B store
    #pragma unroll
    for (int n=0;n<4;++n){
      const int d = n*16 + l16;
      #pragma unroll
      for (int m=0;m<4;++m){
        const int t0 = row0 + wr*64 + m*16 + lg*4;
        bf16x4 v;
        #pragma unroll
        for (int r=0;r<4;++r) v[r] = (bf16)acc[m][n][r];
        *(bf16x4*)&Vt[((size_t)h*64 + d)*2048 + t0] = v;
      }
    }
  } else {
    const float sc = (z==0) ? 0.125f*ts[h]*mw[head_group(h)] : 1.0f;
    bf16* Out = (z==0) ? Qs : Ks;
    #pragma unroll
    for (int m=0;m<4;++m){
      #pragma unroll
      for (int r=0;r<4;++r){
        const int t = row0 + wr*64 + m*16 + lg*4 + r;
        const float* ct = cosT + t*32;
        const float* st = sinT + t*32;
        bf16* dst = Out + ((size_t)h*2048 + t)*64;
        #pragma unroll
        for (int n=0;n<2;++n){
          const int i = n*16 + l16;
          const float c = ct[i], s = st[i];
          const float a1 = acc[m][n][r], a2 = acc[m][n+2][r];
          dst[i]    = (bf16)((a1*c - a2*s)*sc);
          dst[i+32] = (bf16)((a2*c + a1*s)*sc);
        }
      }
    }
  }
}

__global__ __launch_bounds__(256) void gemm_out_kernel(
    const bf16* __restrict__ A, const bf16* __restrict__ B, float* __restrict__ C){
  const int row0 = blockIdx.y*128, col0 = blockIdx.x*128;
  f32x4 acc[4][4];
  gemm_core(A, B, row0, col0, acc);
  const int tid  = threadIdx.x;
  const int wave = tid>>6, lane = tid&63;
  const int l16  = lane&15, lg = lane>>4;
  const int wr   = wave>>1, wc = wave&1;
  #pragma unroll
  for (int m=0;m<4;++m)
    #pragma unroll
    for (int n=0;n<4;++n)
      #pragma unroll
      for (int r=0;r<4;++r){
        size_t idx = (size_t)(row0 + wr*64 + m*16 + lg*4 + r)*2048
                   + col0 + wc*64 + n*16 + l16;
        C[idx] = acc[m][n][r];
      }
}

// ---------------- fused causal attention ----------------
// Proven 8-wave x 16-q-row structure (r5/r8), with:
//  * K/V staged via global_load_lds, source pre-swizzled so LDS slot (row,j)
//    holds global col-block j^(row&7) -- read formulas unchanged (rule #21).
//  * wave-uniform mask branch: per-element causal mask only when k0+63 > qbase
//    (wave's MIN q-row) -- exactly one masked tile per wave.
//  * -4 softmax shift folded into the bias prefetch.
// Double-buffered LDS, one barrier per iteration, complementary-qt pairing.
__global__ __launch_bounds__(512) void attn_kernel(
    const bf16* __restrict__ Qs, const bf16* __restrict__ Ks,
    const bf16* __restrict__ Vt, const bf16* __restrict__ biasb,
    const float* __restrict__ mw, bf16* __restrict__ attout){
  const int n  = blockIdx.x;                       // 0..511
  const int h  = ((n>>8)<<4) | ((n>>4)&15);        // 0..31
  const int qt = (n&256) ? (n&15) : 15-(n&15);     // paired: qt(n)+qt(n+256)=15
  const int tid = threadIdx.x, wid = tid>>6, lane = tid&63;
  const int l16 = lane&15, lg = lane>>4;
  const float w_h = mw[head_group(h)];
  const int qbase = qt*128 + wid*16;
  const int qg0 = qbase + lg*4;                    // +r = this lane's q rows
  const int qtop = qbase + 15;
  const int nkt = 2*qt + 2;

  __shared__ bf16 Kl[2][4096];
  __shared__ bf16 Vl[2][4096];
  __shared__ bf16 plds[8][16][72];

  // gload_lds staging: wave w stages rows w*8..w*8+7; lane -> row w*8+(lane>>3),
  // col-block (lane&7)^(row&7) of the source; HW writes LDS base + lane*16B.
  const int srow = wid*8 + (lane>>3);
  const int sswz = ((lane&7) ^ (srow&7))<<3;
  const bf16* KgS = Ks + (size_t)h*2048*64 + srow*64 + sswz;    // + k0*64
  const bf16* VgS = Vt + ((size_t)h*64 + srow)*2048 + sswz;     // + k0

  // Q fragments (registers, whole kernel)
  const bf16* Qp = Qs + ((size_t)h*2048 + qbase + l16)*64 + lg*8;
  bf16x8 qf0 = *(const bf16x8*)Qp;
  bf16x8 qf1 = *(const bf16x8*)(Qp + 32);

  const bf16* Bg = biasb + (size_t)qg0*2048;       // rows qg0..qg0+3

  f32x4 O[4];
  float l[4] = {0.f,0.f,0.f,0.f};
  #pragma unroll
  for (int c=0;c<4;++c)
    #pragma unroll
    for (int r=0;r<4;++r) O[c][r] = 0.f;

  int rK0[4], rK1[4];
  #pragma unroll
  for (int c=0;c<4;++c){
    const int row = c*16 + l16;
    rK0[c] = row*64 + (((lg  ) ^ (row&7))<<3);
    rK1[c] = row*64 + (((4+lg) ^ (row&7))<<3);
  }

  // bias for tile 0, prefetched (w_h and the -4 exp shift folded in)
  float bc[4][4];
  #pragma unroll
  for (int c=0;c<4;++c)
    #pragma unroll
    for (int r=0;r<4;++r)
      bc[c][r] = w_h * (float)Bg[(size_t)r*2048 + c*16 + l16] - 4.0f;

  // prologue: stage tile 0 into buffer 0
  gload16(KgS, &Kl[0][wid*512]);
  gload16(VgS, &Vl[0][wid*512]);
  __syncthreads();

  int cur = 0;
  for (int kt=0; kt<nkt; ++kt){
    const int k0 = kt*64;
    const bool more = (kt+1 < nkt);
    if (more){
      // stage next tile into the other buffer (all waves; DMA, drained at barrier)
      bf16* kd = cur ? &Kl[0][wid*512] : &Kl[1][wid*512];
      bf16* vd = cur ? &Vl[0][wid*512] : &Vl[1][wid*512];
      gload16(KgS + (size_t)(k0+64)*64, kd);
      gload16(VgS + (k0+64), vd);
    }
    float bn[4][4];
    const bool needb = more && (k0+64 <= qtop);
    if (needb){
      #pragma unroll
      for (int c=0;c<4;++c)
        #pragma unroll
        for (int r=0;r<4;++r)
          bn[c][r] = w_h * (float)Bg[(size_t)r*2048 + (k0+64) + c*16 + l16] - 4.0f;
    }

    if (k0 <= qtop){                       // wave-uniform skip of fully-masked tiles
      // S init = prefetched (w*bias - 4)
      f32x4 S[4];
      #pragma unroll
      for (int c=0;c<4;++c)
        #pragma unroll
        for (int r=0;r<4;++r) S[c][r] = bc[c][r];

      // S += Q K^T from LDS
      __builtin_amdgcn_s_setprio(1);
      #pragma unroll
      for (int c=0;c<4;++c){
        bf16x8 kf0 = *(const bf16x8*)&Kl[cur][rK0[c]];
        bf16x8 kf1 = *(const bf16x8*)&Kl[cur][rK1[c]];
        S[c] = MFMA_BF16(qf0, kf0, S[c]);
        S[c] = MFMA_BF16(qf1, kf1, S[c]);
      }
      __builtin_amdgcn_s_setprio(0);

      // exp; per-element causal mask only when the tile crosses the diagonal
      if (k0 + 63 > qbase){
        #pragma unroll
        for (int c=0;c<4;++c){
          const int kg = k0 + c*16 + l16;
          #pragma unroll
          for (int r=0;r<4;++r){
            float p = __expf(S[c][r]);
            if (kg > qg0+r) p = 0.f;
            S[c][r] = p; l[r] += p;
          }
        }
      } else {
        #pragma unroll
        for (int c=0;c<4;++c)
          #pragma unroll
          for (int r=0;r<4;++r){
            const float p = __expf(S[c][r]);
            S[c][r] = p; l[r] += p;
          }
      }

      // P (C-layout) -> per-wave LDS -> A-fragments
      #pragma unroll
      for (int c=0;c<4;++c)
        #pragma unroll
        for (int r=0;r<4;++r)
          plds[wid][lg*4+r][c*16+l16] = (bf16)S[c][r];
      bf16x8 pf0 = *(const bf16x8*)&plds[wid][l16][lg*8];
      bf16x8 pf1 = *(const bf16x8*)&plds[wid][l16][lg*8+32];

      // O += P * V from LDS
      __builtin_amdgcn_s_setprio(1);
      #pragma unroll
      for (int c=0;c<4;++c){
        bf16x8 vf0 = *(const bf16x8*)&Vl[cur][rK0[c]];
        bf16x8 vf1 = *(const bf16x8*)&Vl[cur][rK1[c]];
        O[c] = MFMA_BF16(pf0, vf0, O[c]);
        O[c] = MFMA_BF16(pf1, vf1, O[c]);
      }
      __builtin_amdgcn_s_setprio(0);
    }

    if (needb){
      #pragma unroll
      for (int c=0;c<4;++c)
        #pragma unroll
        for (int r=0;r<4;++r) bc[c][r] = bn[c][r];
    }
    __syncthreads();                       // drains staging DMA + all LDS reads
    cur ^= (int)more;
  }

  // deferred row-sum reduction (across the 16 lanes of each row group)
  #pragma unroll
  for (int r=0;r<4;++r){
    float v = l[r];
    v += __shfl_xor(v,1);
    v += __shfl_xor(v,2);
    v += __shfl_xor(v,4);
    v += __shfl_xor(v,8);
    l[r] = 1.0f / v;
  }
  #pragma unroll
  for (int c=0;c<4;++c)
    #pragma unroll
    for (int r=0;r<4;++r)
      attout[(size_t)(qg0+r)*2048 + h*64 + c*16 + l16] = (bf16)(O[c][r]*l[r]);
}

// ---------------- launcher ----------------
extern "C" void kernel_launch(void* const* d_in, const int* in_sizes, int n_in,
                              void* d_out, int out_size, void* d_ws, size_t ws_size,
                              hipStream_t stream){
  const float* x    = (const float*)d_in[0];
  const float* bias = (const float*)d_in[2];
  const float* mw   = (const float*)d_in[3];
  const float* Wq   = (const float*)d_in[4];
  const float* Wk   = (const float*)d_in[5];
  const float* Wv   = (const float*)d_in[6];
  const float* Wo   = (const float*)d_in[7];
  const float* ts   = (const float*)d_in[8];
  float* out = (float*)d_out;

  const size_t SZ = (size_t)2048*2048;
  bf16* base = (bf16*)d_ws;
  bf16* xb   = base;
  bf16* Wqb  = base + 1*SZ;
  bf16* Wkb  = base + 2*SZ;
  bf16* Wvb  = base + 3*SZ;
  bf16* Wob  = base + 4*SZ;
  bf16* bb   = base + 5*SZ;
  bf16* Qsb  = base + 6*SZ;
  bf16* Ksb  = base + 7*SZ;
  bf16* Vtb  = base + 8*SZ;
  bf16* att  = base + 9*SZ;
  float* cosT = (float*)(base + 10*SZ);
  float* sinT = cosT + 2048*32;

  CvtArgs ca;
  ca.src[0]=x;  ca.src[1]=Wq;  ca.src[2]=Wk;  ca.src[3]=Wv;  ca.src[4]=Wo;  ca.src[5]=bias;
  ca.dst[0]=xb; ca.dst[1]=Wqb; ca.dst[2]=Wkb; ca.dst[3]=Wvb; ca.dst[4]=Wob; ca.dst[5]=bb;
  const int nb = (int)(SZ/8/256);
  cvt6_kernel<<<dim3(nb,6),256,0,stream>>>(ca, (int)SZ);
  rope_tab_kernel<<<256,256,0,stream>>>(cosT, sinT);
  gemm_qkv_kernel<<<dim3(16,16,3),256,0,stream>>>(xb, Wqb,Wkb,Wvb,
                                                  Qsb,Ksb,Vtb, cosT,sinT, mw,ts);
  attn_kernel<<<512,512,0,stream>>>(Qsb,Ksb,Vtb,bb,mw,att);
  gemm_out_kernel<<<dim3(16,16),256,0,stream>>>(att, Wob, out);
}